// Round 3
// baseline (133.113 us; speedup 1.0000x reference)
//
#include <hip/hip_runtime.h>
#include <stdint.h>

#pragma clang fp contract(off)

#define A_TOTAL 147456   // 128*128*9
#define G 256
#define NANCHOR_BLOCKS 576          // 147456/256
#define TOTAL_BLOCKS (NANCHOR_BLOCKS + G)

// Base anchors (base_size=16, ratios {0.5,1,2}, scales {8,16,32}) — from
// reference _base_anchors() (np.round half-to-even: 11.5->12).
__constant__ float c_bx1[9] = { -84.f, -176.f, -360.f,  -56.f, -120.f, -248.f,  -36.f,  -80.f, -168.f };
__constant__ float c_by1[9] = { -40.f,  -88.f, -184.f,  -56.f, -120.f, -248.f,  -80.f, -168.f, -344.f };
__constant__ float c_bx2[9] = {  99.f,  191.f,  375.f,   71.f,  135.f,  263.f,   51.f,   95.f,  183.f };
__constant__ float c_by2[9] = {  55.f,  103.f,  199.f,   71.f,  135.f,  263.f,   95.f,  183.f,  359.f };
__constant__ float c_area[9] = { 17664.f, 70656.f, 282624.f, 16384.f, 65536.f, 262144.f, 15488.f, 61952.f, 247808.f };

__device__ __forceinline__ unsigned int fenc(float f) {
    unsigned int u = __float_as_uint(f);
    return (u & 0x80000000u) ? ~u : (u | 0x80000000u);
}

__device__ __forceinline__ unsigned long long shfl_down_u64(unsigned long long v, int off) {
    unsigned int lo = (unsigned int)v;
    unsigned int hi = (unsigned int)(v >> 32);
    lo = __shfl_down(lo, off, 64);
    hi = __shfl_down(hi, off, 64);
    return ((unsigned long long)hi << 32) | lo;
}

// Fused kernel. Blocks [0,576): per-anchor max/argmax over gts + label ladder
// (WITHOUT the gt-argmax scatter — k_fix patches those 256 anchors after) +
// bbox transform. Blocks [576,832): per-gt argmax over inside anchors
// (windowed search), writing the winning anchor index to ws.
__global__ __launch_bounds__(256) void k_fused(
    const float* __restrict__ gt, const float* __restrict__ meta,
    int* __restrict__ win, float* __restrict__ out)
{
    __shared__ float4 sbox[G];
    __shared__ float  sarea[G];
    __shared__ unsigned long long red[4];

    const float H = meta[0], W = meta[1];

    if (blockIdx.x >= NANCHOR_BLOCKS) {
        // ---------- per-gt argmax path ----------
        const int g = blockIdx.x - NANCHOR_BLOCKS;
        const float gx1 = gt[4*g+0], gy1 = gt[4*g+1], gx2 = gt[4*g+2], gy2 = gt[4*g+3];
        const float area_b = (gx2 - gx1 + 1.0f) * (gy2 - gy1 + 1.0f);
        const int tx = threadIdx.x & 15, ty = threadIdx.x >> 4;

        constexpr int ibx1[9] = {-84,-176,-360,-56,-120,-248,-36,-80,-168};
        constexpr int iby1[9] = {-40,-88,-184,-56,-120,-248,-80,-168,-344};
        constexpr int ibx2[9] = { 99, 191, 375, 71, 135, 263, 51, 95, 183};
        constexpr int iby2[9] = { 55, 103, 199, 71, 135, 263, 95, 183, 359};
        constexpr int iarea[9] = {17664,70656,282624,16384,65536,262144,15488,61952,247808};

        unsigned long long best = 0ULL;  // < any real encoding
        #pragma unroll
        for (int a = 0; a < 9; ++a) {
            const int xlo_in = (-ibx1[a] + 15) >> 4;
            const int ylo_in = (-iby1[a] + 15) >> 4;
            const int xhi_in = (int)floorf((W - 1.0f - (float)ibx2[a]) * 0.0625f);
            const int yhi_in = (int)floorf((H - 1.0f - (float)iby2[a]) * 0.0625f);
            int xlo = max(max((int)floorf((gx1 - (float)ibx2[a]) * 0.0625f) - 1, xlo_in), 0);
            int xhi = min(min((int)floorf((gx2 - (float)ibx1[a]) * 0.0625f) + 1, xhi_in), 127);
            int ylo = max(max((int)floorf((gy1 - (float)iby2[a]) * 0.0625f) - 1, ylo_in), 0);
            int yhi = min(min((int)floorf((gy2 - (float)iby1[a]) * 0.0625f) + 1, yhi_in), 127);
            const float fa = (float)iarea[a];

            for (int iy = ylo + ty; iy <= yhi; iy += 16) {
                const float ay1 = (float)((iy << 4) + iby1[a]);
                const float ay2 = (float)((iy << 4) + iby2[a]);
                float ih = fminf(ay2, gy2) - fmaxf(ay1, gy1) + 1.0f; ih = fmaxf(ih, 0.0f);
                for (int ix = xlo + tx; ix <= xhi; ix += 16) {
                    const float ax1 = (float)((ix << 4) + ibx1[a]);
                    const float ax2 = (float)((ix << 4) + ibx2[a]);
                    bool inside = (ax1 >= 0.0f) & (ay1 >= 0.0f) & (ax2 < W) & (ay2 < H);
                    float iw = fminf(ax2, gx2) - fmaxf(ax1, gx1) + 1.0f; iw = fmaxf(iw, 0.0f);
                    float inter = iw * ih;
                    float uni = fmaxf(fa + area_b - inter, 1e-8f);
                    float iou = inter / uni;
                    float m = inside ? iou : -1.0f;
                    int n = ((iy << 7) + ix) * 9 + a;
                    unsigned long long e = ((unsigned long long)fenc(m) << 32) | (unsigned int)(~n);
                    if (e > best) best = e;
                }
            }
        }
        for (int off = 32; off >= 1; off >>= 1) {
            unsigned long long o = shfl_down_u64(best, off);
            if (o > best) best = o;
        }
        const int wave = threadIdx.x >> 6, lane = threadIdx.x & 63;
        if (lane == 0) red[wave] = best;
        __syncthreads();
        if (threadIdx.x == 0) {
            unsigned long long v = red[0];
            if (red[1] > v) v = red[1];
            if (red[2] > v) v = red[2];
            if (red[3] > v) v = red[3];
            win[g] = (int)(~(unsigned int)(v & 0xffffffffULL));
        }
        return;
    }

    // ---------- per-anchor path ----------
    const int tid = threadIdx.x;
    {
        float4 b = ((const float4*)gt)[tid];
        sbox[tid] = b;
        sarea[tid] = (b.z - b.x + 1.0f) * (b.w - b.y + 1.0f);
    }
    __syncthreads();

    const int n = blockIdx.x * 256 + tid;
    int k = n / 9;
    int a = n - 9 * k;
    float sx = (float)((k & 127) << 4);
    float sy = (float)((k >> 7) << 4);
    float ax1 = sx + c_bx1[a];
    float ay1 = sy + c_by1[a];
    float ax2 = sx + c_bx2[a];
    float ay2 = sy + c_by2[a];
    bool inside = (ax1 >= 0.0f) & (ay1 >= 0.0f) & (ax2 < W) & (ay2 < H);
    float area_a = c_area[a];

    float bestv = -1.0f;
    int barg = 0;
    #pragma unroll 2
    for (int g = 0; g < G; ++g) {
        float4 bb = sbox[g];
        float iw = fminf(ax2, bb.z) - fmaxf(ax1, bb.x) + 1.0f; iw = fmaxf(iw, 0.0f);
        float ih = fminf(ay2, bb.w) - fmaxf(ay1, bb.y) + 1.0f; ih = fmaxf(ih, 0.0f);
        float inter = iw * ih;
        if (__all(inter == 0.0f)) {
            // iou is exactly 0 for every lane: update matches `0 > bestv`.
            if (bestv < 0.0f) { bestv = 0.0f; barg = g; }
        } else {
            float uni = fmaxf(area_a + sarea[g] - inter, 1e-8f);
            float iou = inter / uni;
            if (iou > bestv) { bestv = iou; barg = g; }   // strict > : first max index
        }
    }

    // Label ladder minus the gt-argmax scatter (k_fix rewrites those anchors).
    float label = -1.0f;
    if (bestv < 0.3f) label = 0.0f;            // NEG_OVERLAP
    if (bestv >= 0.7f) label = 1.0f;           // POS_OVERLAP
    if (!inside) label = -1.0f;                // applied last

    float4 gb = sbox[barg];
    float ew = ax2 - ax1 + 1.0f;
    float eh = ay2 - ay1 + 1.0f;
    float ecx = ax1 + 0.5f * ew;
    float ecy = ay1 + 0.5f * eh;
    float gw = gb.z - gb.x + 1.0f;
    float gh = gb.w - gb.y + 1.0f;
    float gcx = gb.x + 0.5f * gw;
    float gcy = gb.y + 0.5f * gh;
    float t0 = (gcx - ecx) / ew;
    float t1 = (gcy - ecy) / eh;
    float t2 = logf(gw / ew);
    float t3 = logf(gh / eh);
    if (!inside) { t0 = 0.0f; t1 = 0.0f; t2 = 0.0f; t3 = 0.0f; }

    out[n] = label;
    ((float4*)(out + A_TOTAL))[n] = make_float4(t0, t1, t3 * 0.0f + t2, t3);
}

// Patch the 256 winner anchors: recompute their max_overlap (identical iou
// arithmetic -> identical max value), count duplicate winners, full ladder.
// Winners are provably inside (masked iou > 0), so no inside check.
// Duplicate winners write identical values (benign).
__global__ __launch_bounds__(256) void k_fix(
    const float* __restrict__ gt, const int* __restrict__ win,
    float* __restrict__ out)
{
    __shared__ int swin[G];
    const int t = threadIdx.x;
    swin[t] = win[t];
    __syncthreads();

    const int idx = swin[t];
    int k = idx / 9;
    int a = idx - 9 * k;
    float sx = (float)((k & 127) << 4);
    float sy = (float)((k >> 7) << 4);
    float ax1 = sx + c_bx1[a];
    float ay1 = sy + c_by1[a];
    float ax2 = sx + c_bx2[a];
    float ay2 = sy + c_by2[a];
    float area_a = c_area[a];

    float mo = -1.0f;
    for (int g = 0; g < G; ++g) {
        float gx1 = gt[4*g+0], gy1 = gt[4*g+1], gx2 = gt[4*g+2], gy2 = gt[4*g+3];
        float area_b = (gx2 - gx1 + 1.0f) * (gy2 - gy1 + 1.0f);
        float iw = fminf(ax2, gx2) - fmaxf(ax1, gx1) + 1.0f; iw = fmaxf(iw, 0.0f);
        float ih = fminf(ay2, gy2) - fmaxf(ay1, gy1) + 1.0f; ih = fmaxf(ih, 0.0f);
        float inter = iw * ih;
        float uni = fmaxf(area_a + area_b - inter, 1e-8f);
        float iou = inter / uni;
        mo = fmaxf(mo, iou);
    }

    int cnt = 0;
    for (int g = 0; g < G; ++g) cnt += (swin[g] == idx);

    float label = -1.0f;
    if (mo < 0.3f) label = 0.0f;
    label = label + (float)cnt * (1.0f - label);   // .at[].add with duplicates
    if (mo >= 0.7f) label = 1.0f;

    out[idx] = label;
}

extern "C" void kernel_launch(void* const* d_in, const int* in_sizes, int n_in,
                              void* d_out, int out_size, void* d_ws, size_t ws_size,
                              hipStream_t stream) {
    // d_in[0] = scores (unused), d_in[1] = gt_boxes (1,256,4), d_in[2] = metadata (1,3)
    const float* gt   = (const float*)d_in[1];
    const float* meta = (const float*)d_in[2];
    float* out = (float*)d_out;
    int* win = (int*)d_ws;   // 256 ints

    k_fused<<<TOTAL_BLOCKS, 256, 0, stream>>>(gt, meta, win, out);
    k_fix<<<1, 256, 0, stream>>>(gt, win, out);
}

// Round 4
// 96.032 us; speedup vs baseline: 1.3861x; 1.3861x over previous
//
#include <hip/hip_runtime.h>
#include <stdint.h>

#pragma clang fp contract(off)

#define A_TOTAL 147456   // 128*128*9
#define G 256
#define NANCHOR_BLOCKS 576          // 147456/256
#define TOTAL_BLOCKS (NANCHOR_BLOCKS + G)

// Base anchors (base_size=16, ratios {0.5,1,2}, scales {8,16,32}) — from
// reference _base_anchors() (np.round half-to-even: 11.5->12).
__constant__ float c_bx1[9] = { -84.f, -176.f, -360.f,  -56.f, -120.f, -248.f,  -36.f,  -80.f, -168.f };
__constant__ float c_by1[9] = { -40.f,  -88.f, -184.f,  -56.f, -120.f, -248.f,  -80.f, -168.f, -344.f };
__constant__ float c_bx2[9] = {  99.f,  191.f,  375.f,   71.f,  135.f,  263.f,   51.f,   95.f,  183.f };
__constant__ float c_by2[9] = {  55.f,  103.f,  199.f,   71.f,  135.f,  263.f,   95.f,  183.f,  359.f };
__constant__ float c_area[9] = { 17664.f, 70656.f, 282624.f, 16384.f, 65536.f, 262144.f, 15488.f, 61952.f, 247808.f };

__device__ __forceinline__ unsigned int fenc(float f) {
    unsigned int u = __float_as_uint(f);
    return (u & 0x80000000u) ? ~u : (u | 0x80000000u);
}

__device__ __forceinline__ unsigned long long shfl_down_u64(unsigned long long v, int off) {
    unsigned int lo = (unsigned int)v;
    unsigned int hi = (unsigned int)(v >> 32);
    lo = __shfl_down(lo, off, 64);
    hi = __shfl_down(hi, off, 64);
    return ((unsigned long long)hi << 32) | lo;
}

// Fused kernel. Blocks [0,576): per-anchor max/argmax over gts (with block-
// level gt culling) + label ladder (minus gt-argmax scatter; k_fix patches) +
// bbox transform. Blocks [576,832): per-gt argmax over inside anchors.
__global__ __launch_bounds__(256) void k_fused(
    const float* __restrict__ gt, const float* __restrict__ meta,
    int* __restrict__ win, float* __restrict__ out)
{
    __shared__ float4 sfull[G];     // all gt boxes (for bbox lookup by original g)
    __shared__ float4 sbox[G];      // survivor boxes, ascending original g
    __shared__ float  sarea[G];     // survivor areas
    __shared__ int    sg[G];        // survivor original index
    __shared__ int    wcnt[4], woff[4], sS;
    __shared__ unsigned long long red[4];

    const float H = meta[0], W = meta[1];

    if (blockIdx.x >= NANCHOR_BLOCKS) {
        // ---------- per-gt argmax path (windowed search over inside anchors) ----------
        const int g = blockIdx.x - NANCHOR_BLOCKS;
        const float gx1 = gt[4*g+0], gy1 = gt[4*g+1], gx2 = gt[4*g+2], gy2 = gt[4*g+3];
        const float area_b = (gx2 - gx1 + 1.0f) * (gy2 - gy1 + 1.0f);
        const int tx = threadIdx.x & 15, ty = threadIdx.x >> 4;

        constexpr int ibx1[9] = {-84,-176,-360,-56,-120,-248,-36,-80,-168};
        constexpr int iby1[9] = {-40,-88,-184,-56,-120,-248,-80,-168,-344};
        constexpr int ibx2[9] = { 99, 191, 375, 71, 135, 263, 51, 95, 183};
        constexpr int iby2[9] = { 55, 103, 199, 71, 135, 263, 95, 183, 359};
        constexpr int iarea[9] = {17664,70656,282624,16384,65536,262144,15488,61952,247808};

        unsigned long long best = 0ULL;  // < any real encoding
        #pragma unroll
        for (int a = 0; a < 9; ++a) {
            const int xlo_in = (-ibx1[a] + 15) >> 4;
            const int ylo_in = (-iby1[a] + 15) >> 4;
            const int xhi_in = (int)floorf((W - 1.0f - (float)ibx2[a]) * 0.0625f);
            const int yhi_in = (int)floorf((H - 1.0f - (float)iby2[a]) * 0.0625f);
            int xlo = max(max((int)floorf((gx1 - (float)ibx2[a]) * 0.0625f) - 1, xlo_in), 0);
            int xhi = min(min((int)floorf((gx2 - (float)ibx1[a]) * 0.0625f) + 1, xhi_in), 127);
            int ylo = max(max((int)floorf((gy1 - (float)iby2[a]) * 0.0625f) - 1, ylo_in), 0);
            int yhi = min(min((int)floorf((gy2 - (float)iby1[a]) * 0.0625f) + 1, yhi_in), 127);
            const float fa = (float)iarea[a];

            for (int iy = ylo + ty; iy <= yhi; iy += 16) {
                const float ay1 = (float)((iy << 4) + iby1[a]);
                const float ay2 = (float)((iy << 4) + iby2[a]);
                float ih = fminf(ay2, gy2) - fmaxf(ay1, gy1) + 1.0f; ih = fmaxf(ih, 0.0f);
                for (int ix = xlo + tx; ix <= xhi; ix += 16) {
                    const float ax1 = (float)((ix << 4) + ibx1[a]);
                    const float ax2 = (float)((ix << 4) + ibx2[a]);
                    bool inside = (ax1 >= 0.0f) & (ay1 >= 0.0f) & (ax2 < W) & (ay2 < H);
                    float iw = fminf(ax2, gx2) - fmaxf(ax1, gx1) + 1.0f; iw = fmaxf(iw, 0.0f);
                    float inter = iw * ih;
                    float uni = fmaxf(fa + area_b - inter, 1e-8f);
                    float iou = inter / uni;
                    float m = inside ? iou : -1.0f;
                    int n = ((iy << 7) + ix) * 9 + a;
                    unsigned long long e = ((unsigned long long)fenc(m) << 32) | (unsigned int)(~n);
                    if (e > best) best = e;
                }
            }
        }
        for (int off = 32; off >= 1; off >>= 1) {
            unsigned long long o = shfl_down_u64(best, off);
            if (o > best) best = o;
        }
        const int wave = threadIdx.x >> 6, lane = threadIdx.x & 63;
        if (lane == 0) red[wave] = best;
        __syncthreads();
        if (threadIdx.x == 0) {
            unsigned long long v = red[0];
            if (red[1] > v) v = red[1];
            if (red[2] > v) v = red[2];
            if (red[3] > v) v = red[3];
            win[g] = (int)(~(unsigned int)(v & 0xffffffffULL));
        }
        return;
    }

    // ---------- per-anchor path ----------
    const int tid = threadIdx.x;
    const int n0 = blockIdx.x * 256;

    // Dilated block bbox: a gt outside it has inter == 0 exactly for EVERY
    // anchor in this block (margin >= 3 px; see cull proof in journal).
    {
        const int k0 = n0 / 9, k1 = (n0 + 255) / 9;
        int ix_min, ix_max;
        if ((k0 >> 7) == (k1 >> 7)) { ix_min = k0 & 127; ix_max = k1 & 127; }
        else                        { ix_min = 0;        ix_max = 127;      }
        const int iy_min = k0 >> 7, iy_max = k1 >> 7;
        const float bbx1 = (float)(ix_min * 16 - 360 - 4);
        const float bbx2 = (float)(ix_max * 16 + 375 + 4);
        const float bby1 = (float)(iy_min * 16 - 344 - 4);
        const float bby2 = (float)(iy_max * 16 + 359 + 4);

        float4 b = ((const float4*)gt)[tid];
        sfull[tid] = b;
        bool keep = (b.z >= bbx1) & (b.x <= bbx2) & (b.w >= bby1) & (b.y <= bby2);

        unsigned long long m = __ballot(keep);
        const int wave = tid >> 6, lane = tid & 63;
        const int my = __popcll(m & ((1ULL << lane) - 1ULL));
        if (lane == 0) wcnt[wave] = __popcll(m);
        __syncthreads();
        if (tid == 0) {
            int o = 0;
            #pragma unroll
            for (int w = 0; w < 4; ++w) { woff[w] = o; o += wcnt[w]; }
            sS = o;
        }
        __syncthreads();
        if (keep) {
            int p = woff[wave] + my;        // ascending original g across waves
            sbox[p] = b;
            sarea[p] = (b.z - b.x + 1.0f) * (b.w - b.y + 1.0f);
            sg[p] = tid;
        }
        __syncthreads();
    }
    const int S = sS;

    const int n = n0 + tid;
    int k = n / 9;
    int a = n - 9 * k;
    float sx = (float)((k & 127) << 4);
    float sy = (float)((k >> 7) << 4);
    float ax1 = sx + c_bx1[a];
    float ay1 = sy + c_by1[a];
    float ax2 = sx + c_bx2[a];
    float ay2 = sy + c_by2[a];
    bool inside = (ax1 >= 0.0f) & (ay1 >= 0.0f) & (ax2 < W) & (ay2 < H);
    float area_a = c_area[a];

    float bestv = -1.0f;
    int barg = 0;
    #pragma unroll 4
    for (int j = 0; j < S; ++j) {
        float4 bb = sbox[j];
        float iw = fminf(ax2, bb.z) - fmaxf(ax1, bb.x) + 1.0f; iw = fmaxf(iw, 0.0f);
        float ih = fminf(ay2, bb.w) - fmaxf(ay1, bb.y) + 1.0f; ih = fmaxf(ih, 0.0f);
        float inter = iw * ih;
        float uni = fmaxf(area_a + sarea[j] - inter, 1e-8f);
        float iou = inter / uni;
        if (iou > bestv) { bestv = iou; barg = sg[j]; }   // strict > : first max
    }
    // Culled gts all have iou exactly 0. If bestv <= 0 the whole row's max is
    // 0 and iou[0]==0, so jnp.argmax = 0.
    if (bestv <= 0.0f) { bestv = 0.0f; barg = 0; }

    // Label ladder minus the gt-argmax scatter (k_fix rewrites those anchors).
    float label = -1.0f;
    if (bestv < 0.3f) label = 0.0f;            // NEG_OVERLAP
    if (bestv >= 0.7f) label = 1.0f;           // POS_OVERLAP
    if (!inside) label = -1.0f;                // applied last

    float4 gb = sfull[barg];
    float ew = ax2 - ax1 + 1.0f;
    float eh = ay2 - ay1 + 1.0f;
    float ecx = ax1 + 0.5f * ew;
    float ecy = ay1 + 0.5f * eh;
    float gw = gb.z - gb.x + 1.0f;
    float gh = gb.w - gb.y + 1.0f;
    float gcx = gb.x + 0.5f * gw;
    float gcy = gb.y + 0.5f * gh;
    float t0 = (gcx - ecx) / ew;
    float t1 = (gcy - ecy) / eh;
    float t2 = logf(gw / ew);
    float t3 = logf(gh / eh);
    if (!inside) { t0 = 0.0f; t1 = 0.0f; t2 = 0.0f; t3 = 0.0f; }

    out[n] = label;
    ((float4*)(out + A_TOTAL))[n] = make_float4(t0, t1, t2, t3);
}

// Patch the 256 winner anchors. Winners are provably inside with iou>0 (every
// gt overlaps an inside anchor), so no inside handling. gt + win staged in
// LDS — R3's version read gt from global per-iteration and was latency-bound.
__global__ __launch_bounds__(256) void k_fix(
    const float* __restrict__ gt, const int* __restrict__ win,
    float* __restrict__ out)
{
    __shared__ float4 sb[G];
    __shared__ float  sa[G];
    __shared__ int    swin[G];
    const int t = threadIdx.x;
    {
        float4 b = ((const float4*)gt)[t];
        sb[t] = b;
        sa[t] = (b.z - b.x + 1.0f) * (b.w - b.y + 1.0f);
        swin[t] = win[t];
    }
    __syncthreads();

    const int idx = swin[t];
    int k = idx / 9;
    int a = idx - 9 * k;
    float sx = (float)((k & 127) << 4);
    float sy = (float)((k >> 7) << 4);
    float ax1 = sx + c_bx1[a];
    float ay1 = sy + c_by1[a];
    float ax2 = sx + c_bx2[a];
    float ay2 = sy + c_by2[a];
    float area_a = c_area[a];

    float mo = -1.0f;
    int cnt = 0;
    #pragma unroll 4
    for (int g = 0; g < G; ++g) {
        float4 bb = sb[g];
        float iw = fminf(ax2, bb.z) - fmaxf(ax1, bb.x) + 1.0f; iw = fmaxf(iw, 0.0f);
        float ih = fminf(ay2, bb.w) - fmaxf(ay1, bb.y) + 1.0f; ih = fmaxf(ih, 0.0f);
        float inter = iw * ih;
        float uni = fmaxf(area_a + sa[g] - inter, 1e-8f);
        float iou = inter / uni;
        mo = fmaxf(mo, iou);
        cnt += (swin[g] == idx);
    }

    float label = -1.0f;
    if (mo < 0.3f) label = 0.0f;
    label = label + (float)cnt * (1.0f - label);   // .at[].add with duplicates
    if (mo >= 0.7f) label = 1.0f;

    out[idx] = label;
}

extern "C" void kernel_launch(void* const* d_in, const int* in_sizes, int n_in,
                              void* d_out, int out_size, void* d_ws, size_t ws_size,
                              hipStream_t stream) {
    // d_in[0] = scores (unused), d_in[1] = gt_boxes (1,256,4), d_in[2] = metadata (1,3)
    const float* gt   = (const float*)d_in[1];
    const float* meta = (const float*)d_in[2];
    float* out = (float*)d_out;
    int* win = (int*)d_ws;   // 256 ints

    k_fused<<<TOTAL_BLOCKS, 256, 0, stream>>>(gt, meta, win, out);
    k_fix<<<1, 256, 0, stream>>>(gt, win, out);
}